// Round 7
// baseline (572.500 us; speedup 1.0000x reference)
//
#include <hip/hip_runtime.h>
#include <hip/hip_bf16.h>

#define M_TOT 9216      // B*R
#define K1    2816      // IMG+TAG
#define ES    1024
#define LROW  72        // padded LDS row: 9 granules x 8 ushorts (144 B)

typedef __attribute__((ext_vector_type(8))) short bf16x8;
typedef __attribute__((ext_vector_type(4))) float floatx4;

static __device__ __forceinline__ unsigned short f2bf(float f) {
    unsigned int u = __float_as_uint(f);
    u += 0x7fffu + ((u >> 16) & 1u);   // RNE
    return (unsigned short)(u >> 16);
}
// Read 8 consecutive f32, RNE-round to bf16, write 16 B to LDS.
static __device__ __forceinline__ void stage8(const float* g, unsigned short* l) {
    const float4 f0 = *(const float4*)g;
    const float4 f1 = *(const float4*)(g + 4);
    uint4 pk;
    pk.x = (unsigned)f2bf(f0.x) | ((unsigned)f2bf(f0.y) << 16);
    pk.y = (unsigned)f2bf(f0.z) | ((unsigned)f2bf(f0.w) << 16);
    pk.z = (unsigned)f2bf(f1.x) | ((unsigned)f2bf(f1.y) << 16);
    pk.w = (unsigned)f2bf(f1.z) | ((unsigned)f2bf(f1.w) << 16);
    *(uint4*)l = pk;
}

// ============ fused GEMM1 (region = img_tag @ attn_W^T) + attention ============
// grid 144 x block 256. Block: region rows m0..m0+63 x 208 cols -> attention -> boxfeat.
__global__ __launch_bounds__(256, 2) void k_gemm1_attn(
    const float* __restrict__ images,   // [9216][2048]
    const float* __restrict__ tag,      // [9216][768]
    const float* __restrict__ attn_W,   // [200][2816]
    const float* __restrict__ boxes,    // [9216][30]
    const float* __restrict__ pos_emb,  // [257][200]
    unsigned short* __restrict__ boxfeat)  // [9216][256] bf16, cols 200.. zero
{
    __shared__ float ldsR[64][209];                       // 53,504 B (max footprint)
    unsigned short* ldsA = (unsigned short*)&ldsR[0][0];  // [64][LROW] bf16
    unsigned short* ldsB = ldsA + 64 * LROW;              // [208][LROW] bf16

    const int t = threadIdx.x;
    const int lane = t & 63;
    const int w = t >> 6;
    const int quad = lane >> 4;
    const int ln15 = lane & 15;
    const int m0 = blockIdx.x * 64;
    const int rowT = t >> 3;      // 0..31
    const int gsl = t & 7;        // granule 0..7

    floatx4 acc[13] = {};

    for (int kt = 0; kt < 44; ++kt) {
        const int k0 = kt * 64;
        const int useTag = (k0 >= 2048);
        const int astride = useTag ? 768 : 2048;
        const int acoff = useTag ? (k0 - 2048) : k0;
        const float* asrc = useTag ? tag : images;
#pragma unroll
        for (int it = 0; it < 2; ++it) {
            int r = rowT + it * 32;       // 0..63
            stage8(asrc + (long)(m0 + r) * astride + acoff + gsl * 8,
                   &ldsA[r * LROW + gsl * 8]);
        }
#pragma unroll
        for (int it = 0; it < 6; ++it) {
            int r = rowT + it * 32;       // 0..191
            stage8(attn_W + (long)r * K1 + k0 + gsl * 8,
                   &ldsB[r * LROW + gsl * 8]);
        }
        if (rowT < 16) {                  // rows 192..207
            int r = 192 + rowT;
            int sr = (r < 200) ? r : 199; // clamp; region cols 200..207 unused
            stage8(attn_W + (long)sr * K1 + k0 + gsl * 8,
                   &ldsB[r * LROW + gsl * 8]);
        }
        __syncthreads();
#pragma unroll
        for (int s = 0; s < 2; ++s) {
            const int g = s * 4 + quad;   // k-granule 0..7
            bf16x8 a = *(const bf16x8*)&ldsA[(w * 16 + ln15) * LROW + g * 8];
#pragma unroll
            for (int j = 0; j < 13; ++j) {
                bf16x8 b = *(const bf16x8*)&ldsB[(j * 16 + ln15) * LROW + g * 8];
                acc[j] = __builtin_amdgcn_mfma_f32_16x16x32_bf16(a, b, acc[j], 0, 0, 0);
            }
        }
        __syncthreads();
    }

    // accs -> LDS region tile (C layout: row = quad*4+reg, col = lane&15)
#pragma unroll
    for (int j = 0; j < 13; ++j)
#pragma unroll
        for (int r = 0; r < 4; ++r)
            ldsR[w * 16 + quad * 4 + r][j * 16 + ln15] = acc[j][r];
    __syncthreads();

    // attention: wave w handles rows w*16 .. w*16+15
    for (int rr = 0; rr < 16; ++rr) {
        const int ml = w * 16 + rr;
        const int m = m0 + ml;
        float rv[4];
#pragma unroll
        for (int c = 0; c < 4; ++c) {
            int e = lane + c * 64;
            rv[c] = (e < 200) ? ldsR[ml][e] : 0.0f;
        }
        const float* bx = boxes + (long)m * 30;
        int idx[15]; float bw[15], sc[15];
#pragma unroll
        for (int k = 0; k < 15; ++k) {
            int ii = (int)bx[k];
            idx[k] = (ii < 0) ? 0 : (ii > 256 ? 256 : ii);
            bw[k] = bx[15 + k];
        }
#pragma unroll
        for (int k = 0; k < 15; ++k) {
            const float* em = pos_emb + (long)idx[k] * 200;
            float p = 0.0f;
#pragma unroll
            for (int c = 0; c < 4; ++c) {
                int e = lane + c * 64;
                if (e < 200) p += rv[c] * em[e];
            }
            for (int off = 32; off; off >>= 1) p += __shfl_xor(p, off, 64);
            sc[k] = p;
        }
        float mx = -1e30f;
#pragma unroll
        for (int k = 0; k < 15; ++k) { sc[k] = tanhf(sc[k]); mx = fmaxf(mx, sc[k]); }
        float Z = 0.0f, den = 0.0f, pk[15];
#pragma unroll
        for (int k = 0; k < 15; ++k) { pk[k] = __expf(sc[k] - mx); Z += pk[k]; }
#pragma unroll
        for (int k = 0; k < 15; ++k) { pk[k] *= bw[k]; den += pk[k]; }
        den += 1e-6f * Z;                 // softmax*w / (sum + eps) exactly
        const float inv = 1.0f / den;
#pragma unroll
        for (int c = 0; c < 4; ++c) {
            int e = lane + c * 64;
            float o = 0.0f;
            if (e < 200) {
#pragma unroll
                for (int k = 0; k < 15; ++k) o += pk[k] * pos_emb[(long)idx[k] * 200 + e];
                o *= inv;
            }
            boxfeat[(long)m * 256 + e] = f2bf(o);
        }
    }
}

// ============ GEMM2: d_out(f32) = [img|box|tag] @ fc_W^T ============
__global__ __launch_bounds__(256, 2) void k_gemm2(
    const float* __restrict__ images,
    const float* __restrict__ tag,
    const unsigned short* __restrict__ boxfeat, // [9216][256] bf16, cols 200..255 zero
    const float* __restrict__ fc_W,             // [1024][3016]
    float* __restrict__ dout)                   // [9216][1024] f32 (pre-norm)
{
    __shared__ unsigned short ldsA[128 * LROW];
    __shared__ unsigned short ldsB[128 * LROW];
    const int t = threadIdx.x;
    const int lane = t & 63;
    const int w = t >> 6;
    const int quad = lane >> 4;
    const int ln15 = lane & 15;
    const int m0 = blockIdx.x * 128;
    const int n0 = blockIdx.y * 128;
    const int rowT = t >> 3;
    const int gsl = t & 7;
    const int wm = (w & 1) * 64;
    const int wn = (w >> 1) * 64;

    floatx4 acc[4][4] = {};

    for (int kt = 0; kt < 48; ++kt) {
        int seg = (kt < 32) ? 0 : (kt < 36 ? 1 : 2);
        int acoff = (seg == 0) ? kt * 64 : (seg == 1 ? (kt - 32) * 64 : (kt - 36) * 64);
        int boff  = (seg == 0) ? kt * 64 : (seg == 1 ? 2048 + (kt - 32) * 64 : 2248 + (kt - 36) * 64);
        // boxfeat cols 200..255 are zeros, so fc_W cols 2248..2303 read in the
        // kt=35 tile contribute exactly 0 — no fc_W padding needed; they are
        // correctly re-read (against tag) in seg 2.
#pragma unroll
        for (int it = 0; it < 4; ++it) {
            int r = rowT + it * 32;       // 0..127
            if (seg == 1) {               // boxfeat already bf16: copy 16 B
                *(uint4*)&ldsA[r * LROW + gsl * 8] =
                    *(const uint4*)(boxfeat + (long)(m0 + r) * 256 + acoff + gsl * 8);
            } else {
                const float* asrc = (seg == 0) ? images : tag;
                const int astride = (seg == 0) ? 2048 : 768;
                stage8(asrc + (long)(m0 + r) * astride + acoff + gsl * 8,
                       &ldsA[r * LROW + gsl * 8]);
            }
            stage8(fc_W + (long)(n0 + r) * 3016 + boff + gsl * 8,
                   &ldsB[r * LROW + gsl * 8]);
        }
        __syncthreads();
#pragma unroll
        for (int s = 0; s < 2; ++s) {
            const int g = s * 4 + quad;
            bf16x8 a[4], b[4];
#pragma unroll
            for (int i = 0; i < 4; ++i)
                a[i] = *(const bf16x8*)&ldsA[(wm + i * 16 + ln15) * LROW + g * 8];
#pragma unroll
            for (int j = 0; j < 4; ++j)
                b[j] = *(const bf16x8*)&ldsB[(wn + j * 16 + ln15) * LROW + g * 8];
#pragma unroll
            for (int i = 0; i < 4; ++i)
#pragma unroll
                for (int j = 0; j < 4; ++j)
                    acc[i][j] = __builtin_amdgcn_mfma_f32_16x16x32_bf16(a[i], b[j], acc[i][j], 0, 0, 0);
        }
        __syncthreads();
    }
#pragma unroll
    for (int i = 0; i < 4; ++i)
#pragma unroll
        for (int j = 0; j < 4; ++j) {
            int row = m0 + wm + i * 16 + quad * 4;
            int col = n0 + wn + j * 16 + ln15;
#pragma unroll
            for (int r = 0; r < 4; ++r)
                dout[(long)(row + r) * ES + col] = acc[i][j][r];
        }
}

// ============ bias + L2 normalize, IN-PLACE in d_out (f32) ============
__global__ __launch_bounds__(256) void k_norm(
    float* __restrict__ dout,
    const float* __restrict__ bias)
{
    __shared__ float red[4];
    const int m = blockIdx.x;
    const int t = threadIdx.x;
    float* f = dout + (long)m * ES + t * 4;
    float4 v = *(const float4*)f;
    const float4 bs = *(const float4*)(bias + t * 4);
    v.x += bs.x; v.y += bs.y; v.z += bs.z; v.w += bs.w;
    float ss = v.x * v.x + v.y * v.y + v.z * v.z + v.w * v.w;
    for (int off = 32; off; off >>= 1) ss += __shfl_xor(ss, off, 64);
    if ((t & 63) == 0) red[t >> 6] = ss;
    __syncthreads();
    const float total = red[0] + red[1] + red[2] + red[3];
    const float inv = 1.0f / (sqrtf(total) + 1e-8f);
    float4 o;
    o.x = v.x * inv; o.y = v.y * inv; o.z = v.z * inv; o.w = v.w * inv;
    *(float4*)f = o;
}

// ============ launch ============
extern "C" void kernel_launch(void* const* d_in, const int* in_sizes, int n_in,
                              void* d_out, int out_size, void* d_ws, size_t ws_size,
                              hipStream_t stream) {
    const float* images  = (const float*)d_in[0];
    const float* tag     = (const float*)d_in[1];
    const float* boxes   = (const float*)d_in[2];
    const float* pos_emb = (const float*)d_in[3];
    const float* attn_W  = (const float*)d_in[4];
    const float* fc_W    = (const float*)d_in[5];
    const float* fc_b    = (const float*)d_in[6];
    float* out = (float*)d_out;

    // scratch: boxfeat only — 9216*256*2 = 4,718,592 bytes
    unsigned short* boxfeat = (unsigned short*)d_ws;

    k_gemm1_attn<<<dim3(144), 256, 0, stream>>>(images, tag, attn_W, boxes, pos_emb, boxfeat);
    k_gemm2     <<<dim3(72, 8), 256, 0, stream>>>(images, tag, boxfeat, fc_W, out);
    k_norm      <<<dim3(M_TOT), 256, 0, stream>>>(out, fc_b);
}